// Round 12
// baseline (393.520 us; speedup 1.0000x reference)
//
#include <hip/hip_runtime.h>
#include <hip/hip_cooperative_groups.h>

namespace cg = cooperative_groups;

// ---------------------------------------------------------------------------
// GraphSAGE 3-layer forward.
//   h = x[:,4:10]; per layer: mean_agg(h) @ Wl + bl + h @ Wr, relu
// Round-12 changes:
//   - CSR build chain (wtpack+count -> colscan -> scan -> p1fill -> p2fill)
//     fused into ONE cooperative kernel k_build with grid.sync() between
//     phases (5 launches -> 1; removes 4 pipeline-drain boundaries).
//     391 blocks x 256 thr, 3KB LDS -> co-residency trivially satisfied.
//   9 -> 5 launches total.
// ---------------------------------------------------------------------------

typedef __attribute__((ext_vector_type(8))) short bf16x8;   // 8 bf16 = 4 VGPR
typedef __attribute__((ext_vector_type(4))) float f32x4;
typedef __attribute__((ext_vector_type(2))) float f32x2;

constexpr int PB = 256;    // partition pass blocks (== colscan threads, fixed)
constexpr int WTCH = 6144; // weight-prep chunks: 4096 (Wt1) + 2048 (Wt2)
constexpr float F8SCALE = 32.0f;

static __device__ __forceinline__ int imax(int a, int b) { return a > b ? a : b; }

static __device__ __forceinline__ float bfbits_lo(unsigned u) {
    union { unsigned i; float f; } v; v.i = u << 16; return v.f;
}
static __device__ __forceinline__ float bfbits_hi(unsigned u) {
    union { unsigned i; float f; } v; v.i = u & 0xffff0000u; return v.f;
}
static __device__ __forceinline__ unsigned short f2bf(float f) {
    unsigned u = __float_as_uint(f);
    u = (u + 0x7fffu + ((u >> 16) & 1u)) >> 16;
    return (unsigned short)u;
}
static __device__ __forceinline__ unsigned pack2bf(float a, float b) {
    return (unsigned)f2bf(a) | ((unsigned)f2bf(b) << 16);
}
// accumulate 4 fp8-e4m3 bytes (one dword) into a[0..3]
static __device__ __forceinline__ void acc_f8x4(unsigned u, float* a) {
    f32x2 lo = __builtin_amdgcn_cvt_pk_f32_fp8((int)u, false);
    f32x2 hi = __builtin_amdgcn_cvt_pk_f32_fp8((int)u, true);
    a[0] += lo[0]; a[1] += lo[1]; a[2] += hi[0]; a[3] += hi[1];
}
// accumulate a uint4 of bf16 pairs into a[0..7]
static __device__ __forceinline__ void acc_bf8(uint4 v, float* a) {
    a[0] += bfbits_lo(v.x); a[1] += bfbits_hi(v.x);
    a[2] += bfbits_lo(v.y); a[3] += bfbits_hi(v.y);
    a[4] += bfbits_lo(v.z); a[5] += bfbits_hi(v.z);
    a[6] += bfbits_lo(v.w); a[7] += bfbits_hi(v.w);
}

// ---- weight prep (device helpers): fragment-linear packing ------------------
// Chunk c = ((ks*NB + n)*64 + lane); 8 bf16 of W[k..k+7][col] where
// col = n*16 + (lane&15), k = ks*32 + (lane>>4)*8.

static __device__ __forceinline__ void wtfrag_katk(const float* __restrict__ W1,
                                                   const float* __restrict__ W2,
                                                   unsigned short* __restrict__ Wt,
                                                   int K1, int K, int N, int c) {
    int NB = N >> 4;
    int lane = c & 63;
    int n = (c >> 6) % NB;
    int ks = c / (NB << 6);
    int row = n * 16 + (lane & 15);
    int col = ks * 32 + (lane >> 4) * 8;
    unsigned short o[8];
#pragma unroll
    for (int j = 0; j < 8; ++j) {
        int k = col + j;
        float v = (k < K1) ? W1[k * N + row] : W2[(k - K1) * N + row];
        o[j] = f2bf(v);
    }
    *(uint4*)(Wt + (size_t)c * 8) = *(const uint4*)o;
}

static __device__ __forceinline__ void wtfrag_natn(const float* __restrict__ Wa,
                                                   const float* __restrict__ Wb,
                                                   unsigned short* __restrict__ Wt,
                                                   int K, int Nh, int c) {
    int NB = (2 * Nh) >> 4;
    int lane = c & 63;
    int n = (c >> 6) % NB;
    int ks = c / (NB << 6);
    int row = n * 16 + (lane & 15);
    int col = ks * 32 + (lane >> 4) * 8;
    unsigned short o[8];
#pragma unroll
    for (int j = 0; j < 8; ++j) {
        int k = col + j;
        float v = (row < Nh) ? Wa[k * Nh + row] : Wb[k * Nh + (row - Nh)];
        o[j] = f2bf(v);
    }
    *(uint4*)(Wt + (size_t)c * 8) = *(const uint4*)o;
}

// ---- cooperative CSR build: all 5 phases in one kernel ----------------------
// grid = max(nbk, 24+PB) blocks of 256. Phases:
//   0: weight pack (blocks 0..23) + per-(block,bucket) count (24..24+PB)
//   1: column scan of C (blocks 0..nbk)
//   2: bucket-start scan (block 0)
//   3: partition edges into bucket runs (blocks 0..PB)
//   4: per-bucket counting sort -> offs, csr (blocks 0..nbk)

__global__ __launch_bounds__(256) void k_build(const float* __restrict__ Wl1,
                                               const float* __restrict__ Wr1,
                                               const float* __restrict__ Wl2,
                                               const float* __restrict__ Wr2,
                                               unsigned short* __restrict__ Wt1,
                                               unsigned short* __restrict__ Wt2,
                                               const int* __restrict__ src,
                                               const int* __restrict__ dst,
                                               int* __restrict__ C,
                                               int* __restrict__ tot,
                                               int* __restrict__ bstart,
                                               int* __restrict__ offs,
                                               int* __restrict__ csr,
                                               unsigned* __restrict__ ebuf,
                                               int nN, int nE, int nbk, int epb) {
    cg::grid_group grid = cg::this_grid();
    __shared__ int sh[768];
    const int b = blockIdx.x, t = threadIdx.x;

    // ---- phase 0: weight pack + bucket counts
    if (b < 24) {
        int c = b * 256 + t;
        if (c < 4096)      wtfrag_katk(Wl1, Wr1, Wt1, 128, 256, 128, c);
        else if (c < WTCH) wtfrag_natn(Wl2, Wr2, Wt2, 128, 64, c - 4096);
    } else if (b < 24 + PB) {
        int bb = b - 24;
        for (int i = t; i < nbk; i += 256) sh[i] = 0;
        __syncthreads();
        int e0 = bb * epb, e1 = min(e0 + epb, nE);
        for (int i = e0 + t; i < e1; i += 256)
            atomicAdd(&sh[dst[i] >> 8], 1);
        __syncthreads();
        for (int i = t; i < nbk; i += 256)
            C[bb * nbk + i] = sh[i];
    }
    grid.sync();

    // ---- phase 1: exclusive scan down each bucket column (over PB blocks)
    if (b < nbk) {
        int v = C[t * nbk + b];
        sh[t] = v;
        __syncthreads();
        for (int o = 1; o < 256; o <<= 1) {
            int u = (t >= o) ? sh[t - o] : 0;
            __syncthreads();
            sh[t] += u;
            __syncthreads();
        }
        C[t * nbk + b] = sh[t] - v;
        if (t == 255) tot[b] = sh[255];
    }
    grid.sync();

    // ---- phase 2: bucket-start exclusive scan (single block, nbk <= 1024)
    if (b == 0) {
        int base = t * 4;
        int v0 = 0, v1 = 0, v2 = 0, v3 = 0;
        if (base + 3 < nbk) {
            int4 q = *(const int4*)(tot + base);
            v0 = q.x; v1 = q.y; v2 = q.z; v3 = q.w;
        } else {
            if (base < nbk)     v0 = tot[base];
            if (base + 1 < nbk) v1 = tot[base + 1];
            if (base + 2 < nbk) v2 = tot[base + 2];
        }
        int s = v0 + v1 + v2 + v3;
        sh[t] = s;
        __syncthreads();
        for (int o = 1; o < 256; o <<= 1) {
            int u = (t >= o) ? sh[t - o] : 0;
            __syncthreads();
            sh[t] += u;
            __syncthreads();
        }
        int excl = sh[t] - s;
        if (base < nbk)     bstart[base]     = excl;
        if (base + 1 < nbk) bstart[base + 1] = excl + v0;
        if (base + 2 < nbk) bstart[base + 2] = excl + v0 + v1;
        if (base + 3 < nbk) bstart[base + 3] = excl + v0 + v1 + v2;
        if (t == 255) bstart[nbk] = sh[255];
    }
    grid.sync();

    // ---- phase 3: scatter packed (src<<8 | dst&255) into bucket runs
    if (b < PB) {
        for (int i = t; i < nbk; i += 256)
            sh[i] = bstart[i] + C[b * nbk + i];
        __syncthreads();
        int e0 = b * epb, e1 = min(e0 + epb, nE);
        for (int i = e0 + t; i < e1; i += 256) {
            int d = dst[i];
            unsigned s = (unsigned)src[i];
            int p = atomicAdd(&sh[d >> 8], 1);
            ebuf[p] = (s << 8) | (unsigned)(d & 255);
        }
    }
    grid.sync();

    // ---- phase 4: per-bucket counting sort -> offs, csr
    if (b < nbk) {
        int base = bstart[b], end = bstart[b + 1];
        int* h = sh; int* sm = sh + 256; int* cur = sh + 512;
        h[t] = 0;
        __syncthreads();
        for (int i = base + t; i < end; i += 256)
            atomicAdd(&h[ebuf[i] & 255u], 1);
        __syncthreads();
        int v = h[t];
        sm[t] = v;
        __syncthreads();
        for (int o = 1; o < 256; o <<= 1) {
            int u = (t >= o) ? sm[t - o] : 0;
            __syncthreads();
            sm[t] += u;
            __syncthreads();
        }
        int excl = sm[t] - v;
        int node = (b << 8) + t;
        if (node < nN) offs[node] = base + excl;
        cur[t] = base + excl;
        if (b == 0 && t == 0) offs[nN] = nE;
        __syncthreads();
        for (int i = base + t; i < end; i += 256) {
            unsigned e = ebuf[i];
            int p = atomicAdd(&cur[e & 255u], 1);
            csr[p] = (int)(e >> 8);
        }
    }
}

// ---- fused layer 0: mean via 16-lane shfl butterfly + MLP --------------------

__global__ __launch_bounds__(256) void k_l0f(const float* __restrict__ x,
                                             const int* __restrict__ offs,
                                             const int* __restrict__ csr,
                                             const float* __restrict__ Wl,
                                             const float* __restrict__ bl,
                                             const float* __restrict__ Wr,
                                             unsigned short* __restrict__ out,
                                             unsigned char* __restrict__ out8, int nN) {
    int idx = blockIdx.x * 256 + threadIdx.x;
    int node = idx >> 4;
    int j = threadIdx.x & 15;
    if (node >= nN) return;       // whole 16-lane group exits together
    int lo = offs[node], hi = offs[node + 1];
    float a0 = 0, a1 = 0, a2 = 0, a3 = 0, a4 = 0, a5 = 0;
    for (int e = lo + j; e < hi; e += 16) {
        int s = csr[e];
        const float* r = x + (size_t)s * 10 + 4;
        float2 v0 = *(const float2*)(r);
        float2 v1 = *(const float2*)(r + 2);
        float2 v2 = *(const float2*)(r + 4);
        a0 += v0.x; a1 += v0.y; a2 += v1.x; a3 += v1.y; a4 += v2.x; a5 += v2.y;
    }
#pragma unroll
    for (int mask = 1; mask < 16; mask <<= 1) {
        a0 += __shfl_xor(a0, mask); a1 += __shfl_xor(a1, mask);
        a2 += __shfl_xor(a2, mask); a3 += __shfl_xor(a3, mask);
        a4 += __shfl_xor(a4, mask); a5 += __shfl_xor(a5, mask);
    }
    float inv = 1.0f / (float)imax(hi - lo, 1);
    float m[6] = {a0 * inv, a1 * inv, a2 * inv, a3 * inv, a4 * inv, a5 * inv};
    const float* hp = x + (size_t)node * 10 + 4;
    float2 h01 = *(const float2*)hp, h23 = *(const float2*)(hp + 2), h45 = *(const float2*)(hp + 4);
    float h[6] = {h01.x, h01.y, h23.x, h23.y, h45.x, h45.y};
    int j0 = j * 8;
    float4 b0 = *(const float4*)(bl + j0);
    float4 b1 = *(const float4*)(bl + j0 + 4);
    float v[8] = {b0.x, b0.y, b0.z, b0.w, b1.x, b1.y, b1.z, b1.w};
#pragma unroll
    for (int k = 0; k < 6; ++k) {
        float4 w0 = *(const float4*)(Wl + k * 128 + j0);
        float4 w1 = *(const float4*)(Wl + k * 128 + j0 + 4);
        v[0] = fmaf(m[k], w0.x, v[0]); v[1] = fmaf(m[k], w0.y, v[1]);
        v[2] = fmaf(m[k], w0.z, v[2]); v[3] = fmaf(m[k], w0.w, v[3]);
        v[4] = fmaf(m[k], w1.x, v[4]); v[5] = fmaf(m[k], w1.y, v[5]);
        v[6] = fmaf(m[k], w1.z, v[6]); v[7] = fmaf(m[k], w1.w, v[7]);
    }
#pragma unroll
    for (int k = 0; k < 6; ++k) {
        float4 w0 = *(const float4*)(Wr + k * 128 + j0);
        float4 w1 = *(const float4*)(Wr + k * 128 + j0 + 4);
        v[0] = fmaf(h[k], w0.x, v[0]); v[1] = fmaf(h[k], w0.y, v[1]);
        v[2] = fmaf(h[k], w0.z, v[2]); v[3] = fmaf(h[k], w0.w, v[3]);
        v[4] = fmaf(h[k], w1.x, v[4]); v[5] = fmaf(h[k], w1.y, v[5]);
        v[6] = fmaf(h[k], w1.z, v[6]); v[7] = fmaf(h[k], w1.w, v[7]);
    }
#pragma unroll
    for (int t = 0; t < 8; ++t) v[t] = fmaxf(v[t], 0.f);
    unsigned ob[4];
#pragma unroll
    for (int t = 0; t < 4; ++t) ob[t] = pack2bf(v[2 * t], v[2 * t + 1]);
    *(uint4*)(out + (size_t)node * 128 + j0) = *(const uint4*)ob;
    int d0 = __builtin_amdgcn_cvt_pk_fp8_f32(v[0] * F8SCALE, v[1] * F8SCALE, 0, false);
    d0     = __builtin_amdgcn_cvt_pk_fp8_f32(v[2] * F8SCALE, v[3] * F8SCALE, d0, true);
    int d1 = __builtin_amdgcn_cvt_pk_fp8_f32(v[4] * F8SCALE, v[5] * F8SCALE, 0, false);
    d1     = __builtin_amdgcn_cvt_pk_fp8_f32(v[6] * F8SCALE, v[7] * F8SCALE, d1, true);
    uint2 o8; o8.x = (unsigned)d0; o8.y = (unsigned)d1;
    *(uint2*)(out8 + (size_t)node * 128 + j0) = o8;
}

// ---- aggregation -----------------------------------------------------------

// 128-dim fp8 mean -> bf16: thread per (node, 16B chunk), 8x-unrolled edges.
__global__ __launch_bounds__(256) void k_agg128f8(const unsigned char* __restrict__ X,
                                                  const int* __restrict__ offs,
                                                  const int* __restrict__ csr,
                                                  unsigned short* __restrict__ M, int nN) {
    int idx = blockIdx.x * 256 + threadIdx.x;
    int node = idx >> 3;
    int fl = idx & 7;             // features fl*16 .. fl*16+15
    if (node >= nN) return;
    int lo = offs[node], hi = offs[node + 1];
    float a[16];
#pragma unroll
    for (int j = 0; j < 16; ++j) a[j] = 0.f;
    int e = lo;
    for (; e + 8 <= hi; e += 8) {
        uint4 v0 = *(const uint4*)(X + (size_t)csr[e + 0] * 128 + fl * 16);
        uint4 v1 = *(const uint4*)(X + (size_t)csr[e + 1] * 128 + fl * 16);
        uint4 v2 = *(const uint4*)(X + (size_t)csr[e + 2] * 128 + fl * 16);
        uint4 v3 = *(const uint4*)(X + (size_t)csr[e + 3] * 128 + fl * 16);
        uint4 v4 = *(const uint4*)(X + (size_t)csr[e + 4] * 128 + fl * 16);
        uint4 v5 = *(const uint4*)(X + (size_t)csr[e + 5] * 128 + fl * 16);
        uint4 v6 = *(const uint4*)(X + (size_t)csr[e + 6] * 128 + fl * 16);
        uint4 v7 = *(const uint4*)(X + (size_t)csr[e + 7] * 128 + fl * 16);
        acc_f8x4(v0.x, a + 0); acc_f8x4(v0.y, a + 4); acc_f8x4(v0.z, a + 8); acc_f8x4(v0.w, a + 12);
        acc_f8x4(v1.x, a + 0); acc_f8x4(v1.y, a + 4); acc_f8x4(v1.z, a + 8); acc_f8x4(v1.w, a + 12);
        acc_f8x4(v2.x, a + 0); acc_f8x4(v2.y, a + 4); acc_f8x4(v2.z, a + 8); acc_f8x4(v2.w, a + 12);
        acc_f8x4(v3.x, a + 0); acc_f8x4(v3.y, a + 4); acc_f8x4(v3.z, a + 8); acc_f8x4(v3.w, a + 12);
        acc_f8x4(v4.x, a + 0); acc_f8x4(v4.y, a + 4); acc_f8x4(v4.z, a + 8); acc_f8x4(v4.w, a + 12);
        acc_f8x4(v5.x, a + 0); acc_f8x4(v5.y, a + 4); acc_f8x4(v5.z, a + 8); acc_f8x4(v5.w, a + 12);
        acc_f8x4(v6.x, a + 0); acc_f8x4(v6.y, a + 4); acc_f8x4(v6.z, a + 8); acc_f8x4(v6.w, a + 12);
        acc_f8x4(v7.x, a + 0); acc_f8x4(v7.y, a + 4); acc_f8x4(v7.z, a + 8); acc_f8x4(v7.w, a + 12);
    }
    for (; e + 4 <= hi; e += 4) {
        uint4 v0 = *(const uint4*)(X + (size_t)csr[e + 0] * 128 + fl * 16);
        uint4 v1 = *(const uint4*)(X + (size_t)csr[e + 1] * 128 + fl * 16);
        uint4 v2 = *(const uint4*)(X + (size_t)csr[e + 2] * 128 + fl * 16);
        uint4 v3 = *(const uint4*)(X + (size_t)csr[e + 3] * 128 + fl * 16);
        acc_f8x4(v0.x, a + 0); acc_f8x4(v0.y, a + 4); acc_f8x4(v0.z, a + 8); acc_f8x4(v0.w, a + 12);
        acc_f8x4(v1.x, a + 0); acc_f8x4(v1.y, a + 4); acc_f8x4(v1.z, a + 8); acc_f8x4(v1.w, a + 12);
        acc_f8x4(v2.x, a + 0); acc_f8x4(v2.y, a + 4); acc_f8x4(v2.z, a + 8); acc_f8x4(v2.w, a + 12);
        acc_f8x4(v3.x, a + 0); acc_f8x4(v3.y, a + 4); acc_f8x4(v3.z, a + 8); acc_f8x4(v3.w, a + 12);
    }
    for (; e < hi; ++e) {
        uint4 v = *(const uint4*)(X + (size_t)csr[e] * 128 + fl * 16);
        acc_f8x4(v.x, a + 0); acc_f8x4(v.y, a + 4); acc_f8x4(v.z, a + 8); acc_f8x4(v.w, a + 12);
    }
    float inv = 1.0f / (F8SCALE * (float)imax(hi - lo, 1));
    unsigned o[8];
#pragma unroll
    for (int j = 0; j < 8; ++j) o[j] = pack2bf(a[2 * j] * inv, a[2 * j + 1] * inv);
    unsigned short* mp = M + (size_t)node * 128 + fl * 16;
    *(uint4*)(mp)     = *(const uint4*)(o);
    *(uint4*)(mp + 8) = *(const uint4*)(o + 4);
}

// 64-dim bf16 mean + FUSED layer-2 epilogue: out = relu(mean + y2 + bl2)
__global__ __launch_bounds__(256) void k_agg64f(const unsigned short* __restrict__ X,
                                                const int* __restrict__ offs,
                                                const int* __restrict__ csr,
                                                const float* __restrict__ y2,
                                                const float* __restrict__ bl2,
                                                float* __restrict__ out, int nN) {
    int idx = blockIdx.x * 256 + threadIdx.x;
    int node = idx >> 3;
    int fl = idx & 7;             // features fl*8 .. fl*8+7
    if (node >= nN) return;
    int lo = offs[node], hi = offs[node + 1];
    float a[8] = {0, 0, 0, 0, 0, 0, 0, 0};
    int e = lo;
    for (; e + 8 <= hi; e += 8) {
        uint4 v0 = *(const uint4*)(X + (size_t)csr[e + 0] * 64 + fl * 8);
        uint4 v1 = *(const uint4*)(X + (size_t)csr[e + 1] * 64 + fl * 8);
        uint4 v2 = *(const uint4*)(X + (size_t)csr[e + 2] * 64 + fl * 8);
        uint4 v3 = *(const uint4*)(X + (size_t)csr[e + 3] * 64 + fl * 8);
        uint4 v4 = *(const uint4*)(X + (size_t)csr[e + 4] * 64 + fl * 8);
        uint4 v5 = *(const uint4*)(X + (size_t)csr[e + 5] * 64 + fl * 8);
        uint4 v6 = *(const uint4*)(X + (size_t)csr[e + 6] * 64 + fl * 8);
        uint4 v7 = *(const uint4*)(X + (size_t)csr[e + 7] * 64 + fl * 8);
        acc_bf8(v0, a); acc_bf8(v1, a); acc_bf8(v2, a); acc_bf8(v3, a);
        acc_bf8(v4, a); acc_bf8(v5, a); acc_bf8(v6, a); acc_bf8(v7, a);
    }
    for (; e + 4 <= hi; e += 4) {
        uint4 v0 = *(const uint4*)(X + (size_t)csr[e + 0] * 64 + fl * 8);
        uint4 v1 = *(const uint4*)(X + (size_t)csr[e + 1] * 64 + fl * 8);
        uint4 v2 = *(const uint4*)(X + (size_t)csr[e + 2] * 64 + fl * 8);
        uint4 v3 = *(const uint4*)(X + (size_t)csr[e + 3] * 64 + fl * 8);
        acc_bf8(v0, a); acc_bf8(v1, a); acc_bf8(v2, a); acc_bf8(v3, a);
    }
    for (; e < hi; ++e) {
        uint4 v = *(const uint4*)(X + (size_t)csr[e] * 64 + fl * 8);
        acc_bf8(v, a);
    }
    float inv = 1.0f / (float)imax(hi - lo, 1);
    const float* yp = y2 + (size_t)node * 64 + fl * 8;
    float4 ya = *(const float4*)yp;
    float4 yb = *(const float4*)(yp + 4);
    float4 ba = *(const float4*)(bl2 + fl * 8);
    float4 bb = *(const float4*)(bl2 + fl * 8 + 4);
    float* o = out + (size_t)node * 64 + fl * 8;
    *(float4*)(o) = make_float4(fmaxf(fmaf(a[0], inv, ya.x + ba.x), 0.f),
                                fmaxf(fmaf(a[1], inv, ya.y + ba.y), 0.f),
                                fmaxf(fmaf(a[2], inv, ya.z + ba.z), 0.f),
                                fmaxf(fmaf(a[3], inv, ya.w + ba.w), 0.f));
    *(float4*)(o + 4) = make_float4(fmaxf(fmaf(a[4], inv, yb.x + bb.x), 0.f),
                                    fmaxf(fmaf(a[5], inv, yb.y + bb.y), 0.f),
                                    fmaxf(fmaf(a[6], inv, yb.z + bb.z), 0.f),
                                    fmaxf(fmaf(a[7], inv, yb.w + bb.w), 0.f));
}

// ---- MFMA GEMM (layer 1): C = relu( [A0|A1] @ W^T + bias ) ------------------
// Wt fragment-linear. Double-buffered register prefetch across k-steps.

template <int KA, int KB, int N>
__global__ __launch_bounds__(256) void k_mfma(const unsigned short* __restrict__ A0,
                                              const unsigned short* __restrict__ A1,
                                              const unsigned short* __restrict__ Wt,
                                              const float* __restrict__ bias,
                                              unsigned short* __restrict__ Cout, int nN) {
    constexpr int K = KA + KB;
    constexpr int NSTEP = K / 32;
    constexpr int NB = N / 16;
    const int tid = threadIdx.x;
    const int wave = (blockIdx.x * 256 + tid) >> 6;
    const int m0 = wave * 32;
    if (m0 >= nN) return;
    const int lane = tid & 63;
    const int lr = lane & 15;
    const int lk = lane >> 4;

    f32x4 acc[2][NB];
#pragma unroll
    for (int g = 0; g < 2; ++g)
#pragma unroll
        for (int n = 0; n < NB; ++n) acc[g][n] = (f32x4){0.f, 0.f, 0.f, 0.f};

    auto loadA = [&](int kk, bf16x8& a0, bf16x8& a1) {
        const unsigned short* Ap;
        int lda, krel;
        if (KB > 0 && kk >= KA) { Ap = A1; lda = KB; krel = kk - KA; }
        else                    { Ap = A0; lda = KA; krel = kk; }
        a0 = *(const bf16x8*)(Ap + (size_t)(m0 + lr) * lda + krel + lk * 8);
        a1 = *(const bf16x8*)(Ap + (size_t)(m0 + 16 + lr) * lda + krel + lk * 8);
    };
    auto loadB = [&](int ks, bf16x8* b) {
        const unsigned short* Wk = Wt + (((size_t)ks * NB) << 6) * 8 + lane * 8;
#pragma unroll
        for (int n = 0; n < NB; ++n)
            b[n] = *(const bf16x8*)(Wk + ((size_t)n << 6) * 8);
    };

    bf16x8 a0c, a1c, a0n, a1n;
    bf16x8 bc[NB], bn[NB];
    loadA(0, a0c, a1c);
    loadB(0, bc);

#pragma unroll
    for (int ks = 0; ks < NSTEP; ++ks) {
        if (ks + 1 < NSTEP) {
            loadA((ks + 1) * 32, a0n, a1n);
            loadB(ks + 1, bn);
        }
#pragma unroll
        for (int n = 0; n < NB; ++n) {
            acc[0][n] = __builtin_amdgcn_mfma_f32_16x16x32_bf16(a0c, bc[n], acc[0][n], 0, 0, 0);
            acc[1][n] = __builtin_amdgcn_mfma_f32_16x16x32_bf16(a1c, bc[n], acc[1][n], 0, 0, 0);
        }
        if (ks + 1 < NSTEP) {
            a0c = a0n; a1c = a1n;
#pragma unroll
            for (int n = 0; n < NB; ++n) bc[n] = bn[n];
        }
    }

#pragma unroll
    for (int g = 0; g < 2; ++g) {
#pragma unroll
        for (int r = 0; r < 4; ++r) {
            int gm = m0 + g * 16 + lk * 4 + r;
#pragma unroll
            for (int n = 0; n < NB; ++n) {
                float v = fmaxf(acc[g][n][r] + bias[n * 16 + lr], 0.f);
                Cout[(size_t)gm * N + n * 16 + lr] = f2bf(v);
            }
        }
    }
}

// ---- MFMA GEMM (layer 2, merged): z2 = A@Wl2 (bf16), y2 = A@Wr2 (f32) -------
// Wt2 fragment-linear with N-concat cols [Wl2 | Wr2]; K=128, N=128.

__global__ __launch_bounds__(256) void k_mfma_l2(const unsigned short* __restrict__ A0,
                                                 const unsigned short* __restrict__ Wt,
                                                 unsigned short* __restrict__ z2,
                                                 float* __restrict__ y2, int nN) {
    constexpr int K = 128, NSTEP = 4, NB = 8;
    const int tid = threadIdx.x;
    const int wave = (blockIdx.x * 256 + tid) >> 6;
    const int m0 = wave * 32;
    if (m0 >= nN) return;
    const int lane = tid & 63;
    const int lr = lane & 15;
    const int lk = lane >> 4;

    f32x4 acc[2][NB];
#pragma unroll
    for (int g = 0; g < 2; ++g)
#pragma unroll
        for (int n = 0; n < NB; ++n) acc[g][n] = (f32x4){0.f, 0.f, 0.f, 0.f};

    auto loadA = [&](int kk, bf16x8& a0, bf16x8& a1) {
        a0 = *(const bf16x8*)(A0 + (size_t)(m0 + lr) * K + kk + lk * 8);
        a1 = *(const bf16x8*)(A0 + (size_t)(m0 + 16 + lr) * K + kk + lk * 8);
    };
    auto loadB = [&](int ks, bf16x8* b) {
        const unsigned short* Wk = Wt + (((size_t)ks * NB) << 6) * 8 + lane * 8;
#pragma unroll
        for (int n = 0; n < NB; ++n)
            b[n] = *(const bf16x8*)(Wk + ((size_t)n << 6) * 8);
    };

    bf16x8 a0c, a1c, a0n, a1n;
    bf16x8 bc[NB], bn[NB];
    loadA(0, a0c, a1c);
    loadB(0, bc);

#pragma unroll
    for (int ks = 0; ks < NSTEP; ++ks) {
        if (ks + 1 < NSTEP) {
            loadA((ks + 1) * 32, a0n, a1n);
            loadB(ks + 1, bn);
        }
#pragma unroll
        for (int n = 0; n < NB; ++n) {
            acc[0][n] = __builtin_amdgcn_mfma_f32_16x16x32_bf16(a0c, bc[n], acc[0][n], 0, 0, 0);
            acc[1][n] = __builtin_amdgcn_mfma_f32_16x16x32_bf16(a1c, bc[n], acc[1][n], 0, 0, 0);
        }
        if (ks + 1 < NSTEP) {
            a0c = a0n; a1c = a1n;
#pragma unroll
            for (int n = 0; n < NB; ++n) bc[n] = bn[n];
        }
    }

#pragma unroll
    for (int g = 0; g < 2; ++g) {
#pragma unroll
        for (int r = 0; r < 4; ++r) {
            int gm = m0 + g * 16 + lk * 4 + r;
#pragma unroll
            for (int n = 0; n < 4; ++n)
                z2[(size_t)gm * 64 + n * 16 + lr] = f2bf(acc[g][n][r]);
#pragma unroll
            for (int n = 4; n < 8; ++n)
                y2[(size_t)gm * 64 + (n - 4) * 16 + lr] = acc[g][n][r];
        }
    }
}

// ---------------------------------------------------------------------------

extern "C" void kernel_launch(void* const* d_in, const int* in_sizes, int n_in,
                              void* d_out, int out_size, void* d_ws, size_t ws_size,
                              hipStream_t stream) {
    const float* x   = (const float*)d_in[0];
    const int*   ei  = (const int*)d_in[1];
    const float* Wl0 = (const float*)d_in[2];
    const float* bl0 = (const float*)d_in[3];
    const float* Wr0 = (const float*)d_in[4];
    const float* Wl1 = (const float*)d_in[5];
    const float* bl1 = (const float*)d_in[6];
    const float* Wr1 = (const float*)d_in[7];
    const float* Wl2 = (const float*)d_in[8];
    const float* bl2 = (const float*)d_in[9];
    const float* Wr2 = (const float*)d_in[10];

    int nN = in_sizes[0] / 10;
    int nE = in_sizes[1] / 2;
    const int* src = ei;
    const int* dst = ei + nE;
    int nbk = (nN + 255) >> 8;            // 391 buckets (<=512 for LDS)
    int epb = (nE + PB - 1) / PB;         // edges per partition block

    char* ws = (char*)d_ws;
    size_t off = 0;
    auto alloc = [&](size_t bytes) -> char* {
        char* p = ws + off;
        off = (off + bytes + 255) & ~(size_t)255;
        return p;
    };
    unsigned short* out0   = (unsigned short*)alloc((size_t)nN * 128 * 2); // reused as z2 (nN x 64)
    unsigned char*  out0f8 = (unsigned char*)alloc((size_t)nN * 128);
    unsigned short* mean1  = (unsigned short*)alloc((size_t)nN * 128 * 2); // reused as y2 (f32 nN x 64)
    unsigned short* out1   = (unsigned short*)alloc((size_t)nN * 128 * 2);
    unsigned short* Wt1 = (unsigned short*)alloc((size_t)128 * 256 * 2);
    unsigned short* Wt2 = (unsigned short*)alloc((size_t)128 * 128 * 2);
    int* C      = (int*)alloc((size_t)PB * nbk * 4);
    int* tot    = (int*)alloc((size_t)nbk * 4);
    int* bstart = (int*)alloc(((size_t)nbk + 1) * 4);
    int* offs   = (int*)alloc(((size_t)nN + 1) * 4);
    int* csr    = (int*)alloc((size_t)nE * 4);
    unsigned* ebuf = (unsigned*)alloc((size_t)nE * 4);

    unsigned short* z2 = out0;            // out0 dead after layer-1 GEMM
    float*          y2 = (float*)mean1;   // mean1 dead after layer-1 GEMM

    // cooperative CSR build + weight packing (one kernel, 5 phases)
    int gb = (nbk > 24 + PB) ? nbk : (24 + PB);
    void* bargs[] = {(void*)&Wl1, (void*)&Wr1, (void*)&Wl2, (void*)&Wr2,
                     (void*)&Wt1, (void*)&Wt2, (void*)&src, (void*)&dst,
                     (void*)&C, (void*)&tot, (void*)&bstart, (void*)&offs,
                     (void*)&csr, (void*)&ebuf,
                     (void*)&nN, (void*)&nE, (void*)&nbk, (void*)&epb};
    hipLaunchCooperativeKernel((const void*)k_build, dim3(gb), dim3(256),
                               bargs, 0, stream);

    // layer 0 fused (mean via shfl butterfly + K=6 MLP) -> out0 bf16 + out0f8
    k_l0f<<<((size_t)nN * 16 + 255) / 256, 256, 0, stream>>>(
        x, offs, csr, Wl0, bl0, Wr0, out0, out0f8, nN);

    const int gemm_grid = (nN / 32 + 3) / 4 + 1;   // 4 waves/block, 32 rows/wave

    // layer 1: mean1 = agg(out0f8); out1 = relu([mean1|out0] @ W1 + bl1)
    k_agg128f8<<<((size_t)nN * 8 + 255) / 256, 256, 0, stream>>>(out0f8, offs, csr, mean1, nN);
    k_mfma<128, 128, 128><<<gemm_grid, 256, 0, stream>>>(mean1, out0, Wt1, bl1, out1, nN);

    // layer 2 (merged): {z2, y2} = out1 @ [Wl2|Wr2]; out = relu(agg(z2) + y2 + bl2)
    k_mfma_l2<<<gemm_grid, 256, 0, stream>>>(out1, Wt2, z2, y2, nN);
    k_agg64f<<<((size_t)nN * 8 + 255) / 256, 256, 0, stream>>>(
        z2, offs, csr, y2, bl2, (float*)d_out, nN);
}

// Round 13
// 198.705 us; speedup vs baseline: 1.9804x; 1.9804x over previous
//
#include <hip/hip_runtime.h>

// ---------------------------------------------------------------------------
// GraphSAGE 3-layer forward.
//   h = x[:,4:10]; per layer: mean_agg(h) @ Wl + bl + h @ Wr, relu
// Round-13: REVERT to round-11 structure. Round-12's cooperative k_build
//   (grid.sync between CSR-build phases) cost 228us alone: grid barriers on
//   MI355X cross 8 non-coherent XCD L2s via device-scope atomics and are far
//   more expensive than kernel-launch boundaries for short phases.
//   Keeping: separate small launches for the build chain (round-11, 199us).
// ---------------------------------------------------------------------------

typedef __attribute__((ext_vector_type(8))) short bf16x8;   // 8 bf16 = 4 VGPR
typedef __attribute__((ext_vector_type(4))) float f32x4;
typedef __attribute__((ext_vector_type(2))) float f32x2;

constexpr int PB = 256;    // partition pass blocks (== colscan threads, fixed)
constexpr int WTCH = 6144; // weight-prep chunks: 4096 (Wt1) + 2048 (Wt2)
constexpr float F8SCALE = 32.0f;

static __device__ __forceinline__ int imax(int a, int b) { return a > b ? a : b; }

static __device__ __forceinline__ float bfbits_lo(unsigned u) {
    union { unsigned i; float f; } v; v.i = u << 16; return v.f;
}
static __device__ __forceinline__ float bfbits_hi(unsigned u) {
    union { unsigned i; float f; } v; v.i = u & 0xffff0000u; return v.f;
}
static __device__ __forceinline__ unsigned short f2bf(float f) {
    unsigned u = __float_as_uint(f);
    u = (u + 0x7fffu + ((u >> 16) & 1u)) >> 16;
    return (unsigned short)u;
}
static __device__ __forceinline__ unsigned pack2bf(float a, float b) {
    return (unsigned)f2bf(a) | ((unsigned)f2bf(b) << 16);
}
// accumulate 4 fp8-e4m3 bytes (one dword) into a[0..3]
static __device__ __forceinline__ void acc_f8x4(unsigned u, float* a) {
    f32x2 lo = __builtin_amdgcn_cvt_pk_f32_fp8((int)u, false);
    f32x2 hi = __builtin_amdgcn_cvt_pk_f32_fp8((int)u, true);
    a[0] += lo[0]; a[1] += lo[1]; a[2] += hi[0]; a[3] += hi[1];
}
// accumulate a uint4 of bf16 pairs into a[0..7]
static __device__ __forceinline__ void acc_bf8(uint4 v, float* a) {
    a[0] += bfbits_lo(v.x); a[1] += bfbits_hi(v.x);
    a[2] += bfbits_lo(v.y); a[3] += bfbits_hi(v.y);
    a[4] += bfbits_lo(v.z); a[5] += bfbits_hi(v.z);
    a[6] += bfbits_lo(v.w); a[7] += bfbits_hi(v.w);
}

// ---- weight prep (device helpers): fragment-linear packing ------------------
// Chunk c = ((ks*NB + n)*64 + lane); 8 bf16 of W[k..k+7][col] where
// col = n*16 + (lane&15), k = ks*32 + (lane>>4)*8.

static __device__ __forceinline__ void wtfrag_katk(const float* __restrict__ W1,
                                                   const float* __restrict__ W2,
                                                   unsigned short* __restrict__ Wt,
                                                   int K1, int K, int N, int c) {
    int NB = N >> 4;
    int lane = c & 63;
    int n = (c >> 6) % NB;
    int ks = c / (NB << 6);
    int row = n * 16 + (lane & 15);
    int col = ks * 32 + (lane >> 4) * 8;
    unsigned short o[8];
#pragma unroll
    for (int j = 0; j < 8; ++j) {
        int k = col + j;
        float v = (k < K1) ? W1[k * N + row] : W2[(k - K1) * N + row];
        o[j] = f2bf(v);
    }
    *(uint4*)(Wt + (size_t)c * 8) = *(const uint4*)o;
}

static __device__ __forceinline__ void wtfrag_natn(const float* __restrict__ Wa,
                                                   const float* __restrict__ Wb,
                                                   unsigned short* __restrict__ Wt,
                                                   int K, int Nh, int c) {
    int NB = (2 * Nh) >> 4;
    int lane = c & 63;
    int n = (c >> 6) % NB;
    int ks = c / (NB << 6);
    int row = n * 16 + (lane & 15);
    int col = ks * 32 + (lane >> 4) * 8;
    unsigned short o[8];
#pragma unroll
    for (int j = 0; j < 8; ++j) {
        int k = col + j;
        float v = (row < Nh) ? Wa[k * Nh + row] : Wb[k * Nh + (row - Nh)];
        o[j] = f2bf(v);
    }
    *(uint4*)(Wt + (size_t)c * 8) = *(const uint4*)o;
}

// ---- fused prep: blocks [0,24) pack weights; blocks [24, 24+PB) count buckets

__global__ __launch_bounds__(256) void k_prep(const float* __restrict__ Wl1,
                                              const float* __restrict__ Wr1,
                                              const float* __restrict__ Wl2,
                                              const float* __restrict__ Wr2,
                                              unsigned short* __restrict__ Wt1,
                                              unsigned short* __restrict__ Wt2,
                                              const int* __restrict__ dst,
                                              int* __restrict__ C,
                                              int nE, int nbk, int epb) {
    if (blockIdx.x < 24) {
        int c = blockIdx.x * 256 + threadIdx.x;
        if (c < 4096)        wtfrag_katk(Wl1, Wr1, Wt1, 128, 256, 128, c);
        else if (c < WTCH)   wtfrag_natn(Wl2, Wr2, Wt2, 128, 64, c - 4096);
        return;
    }
    __shared__ int h[512];
    int b = blockIdx.x - 24;
    for (int i = threadIdx.x; i < nbk; i += 256) h[i] = 0;
    __syncthreads();
    int e0 = b * epb;
    int e1 = min(e0 + epb, nE);
    for (int i = e0 + threadIdx.x; i < e1; i += 256)
        atomicAdd(&h[dst[i] >> 8], 1);
    __syncthreads();
    for (int i = threadIdx.x; i < nbk; i += 256)
        C[b * nbk + i] = h[i];
}

// ---- graph build: bucket partition + per-bucket counting sort ---------------

__global__ __launch_bounds__(256) void k_colscan(int* __restrict__ C,
                                                 int* __restrict__ tot, int nbk) {
    __shared__ int sm[256];
    int k = blockIdx.x, t = threadIdx.x;
    int v = C[t * nbk + k];
    sm[t] = v;
    __syncthreads();
    for (int o = 1; o < 256; o <<= 1) {
        int u = (t >= o) ? sm[t - o] : 0;
        __syncthreads();
        sm[t] += u;
        __syncthreads();
    }
    C[t * nbk + k] = sm[t] - v;
    if (t == 255) tot[k] = sm[255];
}

// single-block exclusive scan (n <= 1024); writes grand total at offs[n]
__global__ __launch_bounds__(256) void k_scan_a(const int* __restrict__ cnt,
                                                int* __restrict__ offs, int n) {
    __shared__ int sm[256];
    int t = threadIdx.x;
    int base = t * 4;
    int v0 = 0, v1 = 0, v2 = 0, v3 = 0;
    if (base + 3 < n) {
        int4 q = *(const int4*)(cnt + base);
        v0 = q.x; v1 = q.y; v2 = q.z; v3 = q.w;
    } else {
        if (base < n)     v0 = cnt[base];
        if (base + 1 < n) v1 = cnt[base + 1];
        if (base + 2 < n) v2 = cnt[base + 2];
    }
    int s = v0 + v1 + v2 + v3;
    sm[t] = s;
    __syncthreads();
    for (int o = 1; o < 256; o <<= 1) {
        int u = (t >= o) ? sm[t - o] : 0;
        __syncthreads();
        sm[t] += u;
        __syncthreads();
    }
    int excl = sm[t] - s;
    if (base < n)     offs[base]     = excl;
    if (base + 1 < n) offs[base + 1] = excl + v0;
    if (base + 2 < n) offs[base + 2] = excl + v0 + v1;
    if (base + 3 < n) offs[base + 3] = excl + v0 + v1 + v2;
    if (t == 255) offs[n] = sm[255];
}

__global__ __launch_bounds__(256) void k_p1fill(const int* __restrict__ src,
                                                const int* __restrict__ dst,
                                                const int* __restrict__ bstart,
                                                const int* __restrict__ C,
                                                unsigned* __restrict__ ebuf,
                                                int nE, int nbk, int epb) {
    __shared__ int cur[512];
    int b = blockIdx.x;
    for (int i = threadIdx.x; i < nbk; i += 256)
        cur[i] = bstart[i] + C[b * nbk + i];
    __syncthreads();
    int e0 = b * epb;
    int e1 = min(e0 + epb, nE);
    for (int i = e0 + threadIdx.x; i < e1; i += 256) {
        int d = dst[i];
        unsigned s = (unsigned)src[i];
        int p = atomicAdd(&cur[d >> 8], 1);
        ebuf[p] = (s << 8) | (unsigned)(d & 255);
    }
}

__global__ __launch_bounds__(256) void k_p2fill(const unsigned* __restrict__ ebuf,
                                                const int* __restrict__ bstart,
                                                int* __restrict__ offs,
                                                int* __restrict__ csr,
                                                int nN, int nE) {
    __shared__ int h[256], sm[256], cur[256];
    int k = blockIdx.x, t = threadIdx.x;
    int base = bstart[k], end = bstart[k + 1];
    h[t] = 0;
    __syncthreads();
    for (int i = base + t; i < end; i += 256)
        atomicAdd(&h[ebuf[i] & 255u], 1);
    __syncthreads();
    int v = h[t];
    sm[t] = v;
    __syncthreads();
    for (int o = 1; o < 256; o <<= 1) {
        int u = (t >= o) ? sm[t - o] : 0;
        __syncthreads();
        sm[t] += u;
        __syncthreads();
    }
    int excl = sm[t] - v;
    int node = (k << 8) + t;
    if (node < nN) offs[node] = base + excl;
    cur[t] = base + excl;
    if (k == 0 && t == 0) offs[nN] = nE;
    __syncthreads();
    for (int i = base + t; i < end; i += 256) {
        unsigned e = ebuf[i];
        int p = atomicAdd(&cur[e & 255u], 1);
        csr[p] = (int)(e >> 8);
    }
}

// ---- fused layer 0: mean via 16-lane shfl butterfly + MLP --------------------
// 16 threads per node; lane j gathers edges lo+j, lo+j+16, ...; butterfly
// reduce gives all 16 lanes the 6-dim sum; then each lane computes 8 outputs.

__global__ __launch_bounds__(256) void k_l0f(const float* __restrict__ x,
                                             const int* __restrict__ offs,
                                             const int* __restrict__ csr,
                                             const float* __restrict__ Wl,
                                             const float* __restrict__ bl,
                                             const float* __restrict__ Wr,
                                             unsigned short* __restrict__ out,
                                             unsigned char* __restrict__ out8, int nN) {
    int idx = blockIdx.x * 256 + threadIdx.x;
    int node = idx >> 4;
    int j = threadIdx.x & 15;
    if (node >= nN) return;       // whole 16-lane group exits together
    int lo = offs[node], hi = offs[node + 1];
    float a0 = 0, a1 = 0, a2 = 0, a3 = 0, a4 = 0, a5 = 0;
    for (int e = lo + j; e < hi; e += 16) {
        int s = csr[e];
        const float* r = x + (size_t)s * 10 + 4;
        float2 v0 = *(const float2*)(r);
        float2 v1 = *(const float2*)(r + 2);
        float2 v2 = *(const float2*)(r + 4);
        a0 += v0.x; a1 += v0.y; a2 += v1.x; a3 += v1.y; a4 += v2.x; a5 += v2.y;
    }
#pragma unroll
    for (int mask = 1; mask < 16; mask <<= 1) {
        a0 += __shfl_xor(a0, mask); a1 += __shfl_xor(a1, mask);
        a2 += __shfl_xor(a2, mask); a3 += __shfl_xor(a3, mask);
        a4 += __shfl_xor(a4, mask); a5 += __shfl_xor(a5, mask);
    }
    float inv = 1.0f / (float)imax(hi - lo, 1);
    float m[6] = {a0 * inv, a1 * inv, a2 * inv, a3 * inv, a4 * inv, a5 * inv};
    const float* hp = x + (size_t)node * 10 + 4;
    float2 h01 = *(const float2*)hp, h23 = *(const float2*)(hp + 2), h45 = *(const float2*)(hp + 4);
    float h[6] = {h01.x, h01.y, h23.x, h23.y, h45.x, h45.y};
    int j0 = j * 8;
    float4 b0 = *(const float4*)(bl + j0);
    float4 b1 = *(const float4*)(bl + j0 + 4);
    float v[8] = {b0.x, b0.y, b0.z, b0.w, b1.x, b1.y, b1.z, b1.w};
#pragma unroll
    for (int k = 0; k < 6; ++k) {
        float4 w0 = *(const float4*)(Wl + k * 128 + j0);
        float4 w1 = *(const float4*)(Wl + k * 128 + j0 + 4);
        v[0] = fmaf(m[k], w0.x, v[0]); v[1] = fmaf(m[k], w0.y, v[1]);
        v[2] = fmaf(m[k], w0.z, v[2]); v[3] = fmaf(m[k], w0.w, v[3]);
        v[4] = fmaf(m[k], w1.x, v[4]); v[5] = fmaf(m[k], w1.y, v[5]);
        v[6] = fmaf(m[k], w1.z, v[6]); v[7] = fmaf(m[k], w1.w, v[7]);
    }
#pragma unroll
    for (int k = 0; k < 6; ++k) {
        float4 w0 = *(const float4*)(Wr + k * 128 + j0);
        float4 w1 = *(const float4*)(Wr + k * 128 + j0 + 4);
        v[0] = fmaf(h[k], w0.x, v[0]); v[1] = fmaf(h[k], w0.y, v[1]);
        v[2] = fmaf(h[k], w0.z, v[2]); v[3] = fmaf(h[k], w0.w, v[3]);
        v[4] = fmaf(h[k], w1.x, v[4]); v[5] = fmaf(h[k], w1.y, v[5]);
        v[6] = fmaf(h[k], w1.z, v[6]); v[7] = fmaf(h[k], w1.w, v[7]);
    }
#pragma unroll
    for (int t = 0; t < 8; ++t) v[t] = fmaxf(v[t], 0.f);
    unsigned ob[4];
#pragma unroll
    for (int t = 0; t < 4; ++t) ob[t] = pack2bf(v[2 * t], v[2 * t + 1]);
    *(uint4*)(out + (size_t)node * 128 + j0) = *(const uint4*)ob;
    int d0 = __builtin_amdgcn_cvt_pk_fp8_f32(v[0] * F8SCALE, v[1] * F8SCALE, 0, false);
    d0     = __builtin_amdgcn_cvt_pk_fp8_f32(v[2] * F8SCALE, v[3] * F8SCALE, d0, true);
    int d1 = __builtin_amdgcn_cvt_pk_fp8_f32(v[4] * F8SCALE, v[5] * F8SCALE, 0, false);
    d1     = __builtin_amdgcn_cvt_pk_fp8_f32(v[6] * F8SCALE, v[7] * F8SCALE, d1, true);
    uint2 o8; o8.x = (unsigned)d0; o8.y = (unsigned)d1;
    *(uint2*)(out8 + (size_t)node * 128 + j0) = o8;
}

// ---- aggregation -----------------------------------------------------------

// 128-dim fp8 mean -> bf16: thread per (node, 16B chunk), 8x-unrolled edges.
__global__ __launch_bounds__(256) void k_agg128f8(const unsigned char* __restrict__ X,
                                                  const int* __restrict__ offs,
                                                  const int* __restrict__ csr,
                                                  unsigned short* __restrict__ M, int nN) {
    int idx = blockIdx.x * 256 + threadIdx.x;
    int node = idx >> 3;
    int fl = idx & 7;             // features fl*16 .. fl*16+15
    if (node >= nN) return;
    int lo = offs[node], hi = offs[node + 1];
    float a[16];
#pragma unroll
    for (int j = 0; j < 16; ++j) a[j] = 0.f;
    int e = lo;
    for (; e + 8 <= hi; e += 8) {
        uint4 v0 = *(const uint4*)(X + (size_t)csr[e + 0] * 128 + fl * 16);
        uint4 v1 = *(const uint4*)(X + (size_t)csr[e + 1] * 128 + fl * 16);
        uint4 v2 = *(const uint4*)(X + (size_t)csr[e + 2] * 128 + fl * 16);
        uint4 v3 = *(const uint4*)(X + (size_t)csr[e + 3] * 128 + fl * 16);
        uint4 v4 = *(const uint4*)(X + (size_t)csr[e + 4] * 128 + fl * 16);
        uint4 v5 = *(const uint4*)(X + (size_t)csr[e + 5] * 128 + fl * 16);
        uint4 v6 = *(const uint4*)(X + (size_t)csr[e + 6] * 128 + fl * 16);
        uint4 v7 = *(const uint4*)(X + (size_t)csr[e + 7] * 128 + fl * 16);
        acc_f8x4(v0.x, a + 0); acc_f8x4(v0.y, a + 4); acc_f8x4(v0.z, a + 8); acc_f8x4(v0.w, a + 12);
        acc_f8x4(v1.x, a + 0); acc_f8x4(v1.y, a + 4); acc_f8x4(v1.z, a + 8); acc_f8x4(v1.w, a + 12);
        acc_f8x4(v2.x, a + 0); acc_f8x4(v2.y, a + 4); acc_f8x4(v2.z, a + 8); acc_f8x4(v2.w, a + 12);
        acc_f8x4(v3.x, a + 0); acc_f8x4(v3.y, a + 4); acc_f8x4(v3.z, a + 8); acc_f8x4(v3.w, a + 12);
        acc_f8x4(v4.x, a + 0); acc_f8x4(v4.y, a + 4); acc_f8x4(v4.z, a + 8); acc_f8x4(v4.w, a + 12);
        acc_f8x4(v5.x, a + 0); acc_f8x4(v5.y, a + 4); acc_f8x4(v5.z, a + 8); acc_f8x4(v5.w, a + 12);
        acc_f8x4(v6.x, a + 0); acc_f8x4(v6.y, a + 4); acc_f8x4(v6.z, a + 8); acc_f8x4(v6.w, a + 12);
        acc_f8x4(v7.x, a + 0); acc_f8x4(v7.y, a + 4); acc_f8x4(v7.z, a + 8); acc_f8x4(v7.w, a + 12);
    }
    for (; e + 4 <= hi; e += 4) {
        uint4 v0 = *(const uint4*)(X + (size_t)csr[e + 0] * 128 + fl * 16);
        uint4 v1 = *(const uint4*)(X + (size_t)csr[e + 1] * 128 + fl * 16);
        uint4 v2 = *(const uint4*)(X + (size_t)csr[e + 2] * 128 + fl * 16);
        uint4 v3 = *(const uint4*)(X + (size_t)csr[e + 3] * 128 + fl * 16);
        acc_f8x4(v0.x, a + 0); acc_f8x4(v0.y, a + 4); acc_f8x4(v0.z, a + 8); acc_f8x4(v0.w, a + 12);
        acc_f8x4(v1.x, a + 0); acc_f8x4(v1.y, a + 4); acc_f8x4(v1.z, a + 8); acc_f8x4(v1.w, a + 12);
        acc_f8x4(v2.x, a + 0); acc_f8x4(v2.y, a + 4); acc_f8x4(v2.z, a + 8); acc_f8x4(v2.w, a + 12);
        acc_f8x4(v3.x, a + 0); acc_f8x4(v3.y, a + 4); acc_f8x4(v3.z, a + 8); acc_f8x4(v3.w, a + 12);
    }
    for (; e < hi; ++e) {
        uint4 v = *(const uint4*)(X + (size_t)csr[e] * 128 + fl * 16);
        acc_f8x4(v.x, a + 0); acc_f8x4(v.y, a + 4); acc_f8x4(v.z, a + 8); acc_f8x4(v.w, a + 12);
    }
    float inv = 1.0f / (F8SCALE * (float)imax(hi - lo, 1));
    unsigned o[8];
#pragma unroll
    for (int j = 0; j < 8; ++j) o[j] = pack2bf(a[2 * j] * inv, a[2 * j + 1] * inv);
    unsigned short* mp = M + (size_t)node * 128 + fl * 16;
    *(uint4*)(mp)     = *(const uint4*)(o);
    *(uint4*)(mp + 8) = *(const uint4*)(o + 4);
}

// 64-dim bf16 mean + FUSED layer-2 epilogue: out = relu(mean + y2 + bl2)
__global__ __launch_bounds__(256) void k_agg64f(const unsigned short* __restrict__ X,
                                                const int* __restrict__ offs,
                                                const int* __restrict__ csr,
                                                const float* __restrict__ y2,
                                                const float* __restrict__ bl2,
                                                float* __restrict__ out, int nN) {
    int idx = blockIdx.x * 256 + threadIdx.x;
    int node = idx >> 3;
    int fl = idx & 7;             // features fl*8 .. fl*8+7
    if (node >= nN) return;
    int lo = offs[node], hi = offs[node + 1];
    float a[8] = {0, 0, 0, 0, 0, 0, 0, 0};
    int e = lo;
    for (; e + 8 <= hi; e += 8) {
        uint4 v0 = *(const uint4*)(X + (size_t)csr[e + 0] * 64 + fl * 8);
        uint4 v1 = *(const uint4*)(X + (size_t)csr[e + 1] * 64 + fl * 8);
        uint4 v2 = *(const uint4*)(X + (size_t)csr[e + 2] * 64 + fl * 8);
        uint4 v3 = *(const uint4*)(X + (size_t)csr[e + 3] * 64 + fl * 8);
        uint4 v4 = *(const uint4*)(X + (size_t)csr[e + 4] * 64 + fl * 8);
        uint4 v5 = *(const uint4*)(X + (size_t)csr[e + 5] * 64 + fl * 8);
        uint4 v6 = *(const uint4*)(X + (size_t)csr[e + 6] * 64 + fl * 8);
        uint4 v7 = *(const uint4*)(X + (size_t)csr[e + 7] * 64 + fl * 8);
        acc_bf8(v0, a); acc_bf8(v1, a); acc_bf8(v2, a); acc_bf8(v3, a);
        acc_bf8(v4, a); acc_bf8(v5, a); acc_bf8(v6, a); acc_bf8(v7, a);
    }
    for (; e + 4 <= hi; e += 4) {
        uint4 v0 = *(const uint4*)(X + (size_t)csr[e + 0] * 64 + fl * 8);
        uint4 v1 = *(const uint4*)(X + (size_t)csr[e + 1] * 64 + fl * 8);
        uint4 v2 = *(const uint4*)(X + (size_t)csr[e + 2] * 64 + fl * 8);
        uint4 v3 = *(const uint4*)(X + (size_t)csr[e + 3] * 64 + fl * 8);
        acc_bf8(v0, a); acc_bf8(v1, a); acc_bf8(v2, a); acc_bf8(v3, a);
    }
    for (; e < hi; ++e) {
        uint4 v = *(const uint4*)(X + (size_t)csr[e] * 64 + fl * 8);
        acc_bf8(v, a);
    }
    float inv = 1.0f / (float)imax(hi - lo, 1);
    const float* yp = y2 + (size_t)node * 64 + fl * 8;
    float4 ya = *(const float4*)yp;
    float4 yb = *(const float4*)(yp + 4);
    float4 ba = *(const float4*)(bl2 + fl * 8);
    float4 bb = *(const float4*)(bl2 + fl * 8 + 4);
    float* o = out + (size_t)node * 64 + fl * 8;
    *(float4*)(o) = make_float4(fmaxf(fmaf(a[0], inv, ya.x + ba.x), 0.f),
                                fmaxf(fmaf(a[1], inv, ya.y + ba.y), 0.f),
                                fmaxf(fmaf(a[2], inv, ya.z + ba.z), 0.f),
                                fmaxf(fmaf(a[3], inv, ya.w + ba.w), 0.f));
    *(float4*)(o + 4) = make_float4(fmaxf(fmaf(a[4], inv, yb.x + bb.x), 0.f),
                                    fmaxf(fmaf(a[5], inv, yb.y + bb.y), 0.f),
                                    fmaxf(fmaf(a[6], inv, yb.z + bb.z), 0.f),
                                    fmaxf(fmaf(a[7], inv, yb.w + bb.w), 0.f));
}

// ---- MFMA GEMM (layer 1): C = relu( [A0|A1] @ W^T + bias ) ------------------
// Wt fragment-linear. Double-buffered register prefetch across k-steps.

template <int KA, int KB, int N>
__global__ __launch_bounds__(256) void k_mfma(const unsigned short* __restrict__ A0,
                                              const unsigned short* __restrict__ A1,
                                              const unsigned short* __restrict__ Wt,
                                              const float* __restrict__ bias,
                                              unsigned short* __restrict__ Cout, int nN) {
    constexpr int K = KA + KB;
    constexpr int NSTEP = K / 32;
    constexpr int NB = N / 16;
    const int tid = threadIdx.x;
    const int wave = (blockIdx.x * 256 + tid) >> 6;
    const int m0 = wave * 32;
    if (m0 >= nN) return;
    const int lane = tid & 63;
    const int lr = lane & 15;
    const int lk = lane >> 4;

    f32x4 acc[2][NB];
#pragma unroll
    for (int g = 0; g < 2; ++g)
#pragma unroll
        for (int n = 0; n < NB; ++n) acc[g][n] = (f32x4){0.f, 0.f, 0.f, 0.f};

    auto loadA = [&](int kk, bf16x8& a0, bf16x8& a1) {
        const unsigned short* Ap;
        int lda, krel;
        if (KB > 0 && kk >= KA) { Ap = A1; lda = KB; krel = kk - KA; }
        else                    { Ap = A0; lda = KA; krel = kk; }
        a0 = *(const bf16x8*)(Ap + (size_t)(m0 + lr) * lda + krel + lk * 8);
        a1 = *(const bf16x8*)(Ap + (size_t)(m0 + 16 + lr) * lda + krel + lk * 8);
    };
    auto loadB = [&](int ks, bf16x8* b) {
        const unsigned short* Wk = Wt + (((size_t)ks * NB) << 6) * 8 + lane * 8;
#pragma unroll
        for (int n = 0; n < NB; ++n)
            b[n] = *(const bf16x8*)(Wk + ((size_t)n << 6) * 8);
    };

    bf16x8 a0c, a1c, a0n, a1n;
    bf16x8 bc[NB], bn[NB];
    loadA(0, a0c, a1c);
    loadB(0, bc);

#pragma unroll
    for (int ks = 0; ks < NSTEP; ++ks) {
        if (ks + 1 < NSTEP) {
            loadA((ks + 1) * 32, a0n, a1n);
            loadB(ks + 1, bn);
        }
#pragma unroll
        for (int n = 0; n < NB; ++n) {
            acc[0][n] = __builtin_amdgcn_mfma_f32_16x16x32_bf16(a0c, bc[n], acc[0][n], 0, 0, 0);
            acc[1][n] = __builtin_amdgcn_mfma_f32_16x16x32_bf16(a1c, bc[n], acc[1][n], 0, 0, 0);
        }
        if (ks + 1 < NSTEP) {
            a0c = a0n; a1c = a1n;
#pragma unroll
            for (int n = 0; n < NB; ++n) bc[n] = bn[n];
        }
    }

#pragma unroll
    for (int g = 0; g < 2; ++g) {
#pragma unroll
        for (int r = 0; r < 4; ++r) {
            int gm = m0 + g * 16 + lk * 4 + r;
#pragma unroll
            for (int n = 0; n < NB; ++n) {
                float v = fmaxf(acc[g][n][r] + bias[n * 16 + lr], 0.f);
                Cout[(size_t)gm * N + n * 16 + lr] = f2bf(v);
            }
        }
    }
}

// ---- MFMA GEMM (layer 2, merged): z2 = A@Wl2 (bf16), y2 = A@Wr2 (f32) -------
// Wt2 fragment-linear with N-concat cols [Wl2 | Wr2]; K=128, N=128.

__global__ __launch_bounds__(256) void k_mfma_l2(const unsigned short* __restrict__ A0,
                                                 const unsigned short* __restrict__ Wt,
                                                 unsigned short* __restrict__ z2,
                                                 float* __restrict__ y2, int nN) {
    constexpr int K = 128, NSTEP = 4, NB = 8;
    const int tid = threadIdx.x;
    const int wave = (blockIdx.x * 256 + tid) >> 6;
    const int m0 = wave * 32;
    if (m0 >= nN) return;
    const int lane = tid & 63;
    const int lr = lane & 15;
    const int lk = lane >> 4;

    f32x4 acc[2][NB];
#pragma unroll
    for (int g = 0; g < 2; ++g)
#pragma unroll
        for (int n = 0; n < NB; ++n) acc[g][n] = (f32x4){0.f, 0.f, 0.f, 0.f};

    auto loadA = [&](int kk, bf16x8& a0, bf16x8& a1) {
        a0 = *(const bf16x8*)(A0 + (size_t)(m0 + lr) * K + kk + lk * 8);
        a1 = *(const bf16x8*)(A0 + (size_t)(m0 + 16 + lr) * K + kk + lk * 8);
    };
    auto loadB = [&](int ks, bf16x8* b) {
        const unsigned short* Wk = Wt + (((size_t)ks * NB) << 6) * 8 + lane * 8;
#pragma unroll
        for (int n = 0; n < NB; ++n)
            b[n] = *(const bf16x8*)(Wk + ((size_t)n << 6) * 8);
    };

    bf16x8 a0c, a1c, a0n, a1n;
    bf16x8 bc[NB], bn[NB];
    loadA(0, a0c, a1c);
    loadB(0, bc);

#pragma unroll
    for (int ks = 0; ks < NSTEP; ++ks) {
        if (ks + 1 < NSTEP) {
            loadA((ks + 1) * 32, a0n, a1n);
            loadB(ks + 1, bn);
        }
#pragma unroll
        for (int n = 0; n < NB; ++n) {
            acc[0][n] = __builtin_amdgcn_mfma_f32_16x16x32_bf16(a0c, bc[n], acc[0][n], 0, 0, 0);
            acc[1][n] = __builtin_amdgcn_mfma_f32_16x16x32_bf16(a1c, bc[n], acc[1][n], 0, 0, 0);
        }
        if (ks + 1 < NSTEP) {
            a0c = a0n; a1c = a1n;
#pragma unroll
            for (int n = 0; n < NB; ++n) bc[n] = bn[n];
        }
    }

#pragma unroll
    for (int g = 0; g < 2; ++g) {
#pragma unroll
        for (int r = 0; r < 4; ++r) {
            int gm = m0 + g * 16 + lk * 4 + r;
#pragma unroll
            for (int n = 0; n < 4; ++n)
                z2[(size_t)gm * 64 + n * 16 + lr] = f2bf(acc[g][n][r]);
#pragma unroll
            for (int n = 4; n < 8; ++n)
                y2[(size_t)gm * 64 + (n - 4) * 16 + lr] = acc[g][n][r];
        }
    }
}

// ---------------------------------------------------------------------------

extern "C" void kernel_launch(void* const* d_in, const int* in_sizes, int n_in,
                              void* d_out, int out_size, void* d_ws, size_t ws_size,
                              hipStream_t stream) {
    const float* x   = (const float*)d_in[0];
    const int*   ei  = (const int*)d_in[1];
    const float* Wl0 = (const float*)d_in[2];
    const float* bl0 = (const float*)d_in[3];
    const float* Wr0 = (const float*)d_in[4];
    const float* Wl1 = (const float*)d_in[5];
    const float* bl1 = (const float*)d_in[6];
    const float* Wr1 = (const float*)d_in[7];
    const float* Wl2 = (const float*)d_in[8];
    const float* bl2 = (const float*)d_in[9];
    const float* Wr2 = (const float*)d_in[10];

    const int nN = in_sizes[0] / 10;
    const int nE = in_sizes[1] / 2;
    const int* src = ei;
    const int* dst = ei + nE;
    const int nbk = (nN + 255) >> 8;            // 391 buckets (<=512 for LDS)
    const int epb = (nE + PB - 1) / PB;         // edges per partition block

    char* ws = (char*)d_ws;
    size_t off = 0;
    auto alloc = [&](size_t bytes) -> char* {
        char* p = ws + off;
        off = (off + bytes + 255) & ~(size_t)255;
        return p;
    };
    unsigned short* out0   = (unsigned short*)alloc((size_t)nN * 128 * 2); // reused as z2 (nN x 64)
    unsigned char*  out0f8 = (unsigned char*)alloc((size_t)nN * 128);
    unsigned short* mean1  = (unsigned short*)alloc((size_t)nN * 128 * 2); // reused as y2 (f32 nN x 64)
    unsigned short* out1   = (unsigned short*)alloc((size_t)nN * 128 * 2);
    unsigned short* Wt1 = (unsigned short*)alloc((size_t)128 * 256 * 2);
    unsigned short* Wt2 = (unsigned short*)alloc((size_t)128 * 128 * 2);
    int* C      = (int*)alloc((size_t)PB * nbk * 4);
    int* tot    = (int*)alloc((size_t)nbk * 4);
    int* bstart = (int*)alloc(((size_t)nbk + 1) * 4);
    int* offs   = (int*)alloc(((size_t)nN + 1) * 4);
    int* csr    = (int*)alloc((size_t)nE * 4);
    unsigned* ebuf = (unsigned*)alloc((size_t)nE * 4);

    unsigned short* z2 = out0;            // out0 dead after layer-1 GEMM
    float*          y2 = (float*)mean1;   // mean1 dead after layer-1 GEMM

    // prep: weight packing (blocks 0..23) + bucket counting (blocks 24..279)
    k_prep<<<24 + PB, 256, 0, stream>>>(Wl1, Wr1, Wl2, Wr2, Wt1, Wt2, dst, C, nE, nbk, epb);
    k_colscan<<<nbk, 256, 0, stream>>>(C, tot, nbk);
    k_scan_a<<<1, 256, 0, stream>>>(tot, bstart, nbk);
    k_p1fill<<<PB, 256, 0, stream>>>(src, dst, bstart, C, ebuf, nE, nbk, epb);
    k_p2fill<<<nbk, 256, 0, stream>>>(ebuf, bstart, offs, csr, nN, nE);

    // layer 0 fused (mean via shfl butterfly + K=6 MLP) -> out0 bf16 + out0f8
    k_l0f<<<((size_t)nN * 16 + 255) / 256, 256, 0, stream>>>(
        x, offs, csr, Wl0, bl0, Wr0, out0, out0f8, nN);

    const int gemm_grid = (nN / 32 + 3) / 4 + 1;   // 4 waves/block, 32 rows/wave

    // layer 1: mean1 = agg(out0f8); out1 = relu([mean1|out0] @ W1 + bl1)
    k_agg128f8<<<((size_t)nN * 8 + 255) / 256, 256, 0, stream>>>(out0f8, offs, csr, mean1, nN);
    k_mfma<128, 128, 128><<<gemm_grid, 256, 0, stream>>>(mean1, out0, Wt1, bl1, out1, nN);

    // layer 2 (merged): {z2, y2} = out1 @ [Wl2|Wr2]; out = relu(agg(z2) + y2 + bl2)
    k_mfma_l2<<<gemm_grid, 256, 0, stream>>>(out1, Wt2, z2, y2, nN);
    k_agg64f<<<((size_t)nN * 8 + 255) / 256, 256, 0, stream>>>(
        z2, offs, csr, y2, bl2, (float*)d_out, nN);
}